// Round 15
// baseline (11982.531 us; speedup 1.0000x reference)
//
#include <hip/hip_runtime.h>
#include <hip/hip_bf16.h>
#include <stdint.h>

// Decoder: 2-layer LSTM, B=2048, T=96, H=1024, teacher forcing=1.0.
// Round 15: R14 (both operands as register fragments, no LDS/barriers in
// K-loop) with per-wave tile doubled to 128b x 128g: af[8]+wf[8] (16KB) per
// 64 MFMA = intensity 64 FLOP/B (+50% over R14's 43), acc 8x8 f32x4 in AGPRs.
// Blocks = 128 thr (2 waves, wg=w), tile 128b x 256g; grid 512 = 256 L2 +
// 256 L1; 2 blocks/CU = 1 wave/SIMD. hst padded 36 (bank fix); c prefetched.

#define BB  2048
#define TT  96
#define NG  4096
#define NT0 34        // L1 K-iters (K=1088 = 2x32 x-part + 32x32 h-part)
#define NT1 64        // L2 K-iters (K=2048)

typedef __bf16 bf16;
typedef __bf16 bf16x8 __attribute__((ext_vector_type(8)));
typedef float  f32x4  __attribute__((ext_vector_type(4)));

__device__ __forceinline__ float sigm(float x) { return 1.0f / (1.0f + __expf(-x)); }
__device__ __forceinline__ float ftanh(float x) { return 2.0f / (1.0f + __expf(-2.0f * x)) - 1.0f; }

#define SB() __builtin_amdgcn_sched_barrier(0)

// ---------------- prep kernels ----------------
// Gate-interleaved n' = h*4 + gate (orig row n = (n'&3)*1024 + (n'>>2)).
// Wfrag: [panel(256g)][kt][wg(2)][gf(8)][lane(64)][j(8)] (R14 layout).
// Afrag (H, X): tile (b>>4, k>>3) of 16x8 stored contiguous 128 elems:
//   off = ((b>>4)*K8 + (k>>3))*128 + (b&15)*8 + (k&7);  K8 = 128 (H), 8 (X).

__global__ __launch_bounds__(256) void build_wf1(const float* __restrict__ Wih1,
                                                 const float* __restrict__ Whh1,
                                                 bf16* __restrict__ Wf) {
  int idx = blockIdx.x * 256 + threadIdx.x;      // 16*64*8192
  if (idx >= 16 * NT1 * 8192) return;
  int j = idx & 7, lane = (idx >> 3) & 63, gf = (idx >> 9) & 7;
  int wg = (idx >> 12) & 1, kt = (idx >> 13) & 63, panel = idx >> 19;
  int np = panel * 256 + wg * 128 + gf * 16 + (lane & 15);
  int k  = kt * 32 + ((lane >> 4) << 3) + j;
  int n  = (np & 3) * 1024 + (np >> 2);
  float v = (k < 1024) ? Wih1[n * 1024 + k] : Whh1[n * 1024 + (k - 1024)];
  Wf[idx] = (bf16)v;
}

__global__ __launch_bounds__(256) void build_wf0(const float* __restrict__ Wih0,
                                                 const float* __restrict__ Whh0,
                                                 bf16* __restrict__ Wf) {
  int idx = blockIdx.x * 256 + threadIdx.x;      // 16*34*8192
  if (idx >= 16 * NT0 * 8192) return;
  int j = idx & 7, lane = (idx >> 3) & 63, gf = (idx >> 9) & 7;
  int wg = (idx >> 12) & 1;
  int rem = idx >> 13;
  int kt = rem % NT0, panel = rem / NT0;
  int np = panel * 256 + wg * 128 + gf * 16 + (lane & 15);
  int k  = kt * 32 + ((lane >> 4) << 3) + j;
  int n  = (np & 3) * 1024 + (np >> 2);
  float v;
  if (k < 60)      v = Wih0[n * 60 + k];
  else if (k < 64) v = 0.0f;
  else             v = Whh0[n * 1024 + (k - 64)];
  Wf[idx] = (bf16)v;
}

__global__ __launch_bounds__(256) void perm_bias(const float* __restrict__ b0,
                                                 const float* __restrict__ b1,
                                                 float* __restrict__ b0p,
                                                 float* __restrict__ b1p) {
  int idx = blockIdx.x * 256 + threadIdx.x;
  if (idx >= NG) return;
  int n = (idx & 3) * 1024 + (idx >> 2);
  b0p[idx] = b0[n];
  b1p[idx] = b1[n];
}

// Xf: per-t slab of 2048*64 elems, 16x8-tiled (K8 = 8)
__global__ __launch_bounds__(256) void build_xf(
    const float* __restrict__ dec, const float* __restrict__ ty, const float* __restrict__ lec,
    const int* __restrict__ gid, const int* __restrict__ cp, const int* __restrict__ cct,
    const int* __restrict__ cpt, const int* __restrict__ ccl,
    const float* __restrict__ gemb, const float* __restrict__ ep, const float* __restrict__ ect,
    const float* __restrict__ ept, const float* __restrict__ ecl,
    bf16* __restrict__ Xf) {
  int idx = blockIdx.x * 256 + threadIdx.x;  // over B*T
  if (idx >= BB * TT) return;
  int b = idx / TT, t = idx % TT;
  float xv[64];
  xv[0] = (t == 0) ? lec[b] : ty[b * TT + t - 1];
  const float* d = dec + (size_t)idx * 32;
  #pragma unroll
  for (int k = 0; k < 32; ++k) xv[1 + k] = d[k];
  const float* e;
  e = ep  + cp[b]  * 4;  for (int j = 0; j < 4;  ++j) xv[33 + j] = e[j];
  e = ect + cct[b] * 2;  for (int j = 0; j < 2;  ++j) xv[37 + j] = e[j];
  e = ept + cpt[b] * 3;  for (int j = 0; j < 3;  ++j) xv[39 + j] = e[j];
  e = ecl + ccl[b] * 2;  for (int j = 0; j < 2;  ++j) xv[42 + j] = e[j];
  e = gemb + gid[b] * 16; for (int j = 0; j < 16; ++j) xv[44 + j] = e[j];
  for (int j = 60; j < 64; ++j) xv[j] = 0.0f;
  bf16* slab = Xf + (size_t)t * BB * 64;
  int bt = b >> 4, bl = b & 15;
  #pragma unroll
  for (int k = 0; k < 64; ++k)
    slab[((size_t)(bt * 8 + (k >> 3)) << 7) + bl * 8 + (k & 7)] = (bf16)xv[k];
}

// enc state -> Hf fragment layout (K8=128) + transposed c ([h][b])
__global__ __launch_bounds__(256) void init_state(const float* __restrict__ enc_h,
                                                  const float* __restrict__ enc_c,
                                                  bf16* __restrict__ H1b,
                                                  bf16* __restrict__ H2b,
                                                  float* __restrict__ c1t,
                                                  float* __restrict__ c2t) {
  int idx = blockIdx.x * 256 + threadIdx.x;  // over B*H
  if (idx >= BB * 1024) return;
  int b = idx >> 10, h = idx & 1023;
  size_t off = ((size_t)((b >> 4) * 128 + (h >> 3)) << 7) + ((b & 15) << 3) + (h & 7);
  H1b[off] = (bf16)enc_h[idx];
  H2b[off] = (bf16)enc_h[(size_t)BB * 1024 + idx];
  c1t[(size_t)h * BB + b] = enc_c[idx];
  c2t[(size_t)h * BB + b] = enc_c[(size_t)BB * 1024 + idx];
}

// ---------------- streaming GEMM + fused cell: 128b x 256g, 2 waves --------
// gates(b,n') = A(b,:).W(n',:). mfma(wf, af): lane's f32x4 = {i,f,g,o} of one
// (b,h) cell: h = (tn>>2) + w*32 + gf*4 + u, b = tm + bf*16 + l15.
// Both operands stream global->reg; 64 MFMA per 16 x 1KB loads (intensity 64).

template <int MODE>
__device__ __forceinline__ void body(
    int tm, int tn, int t,
    const bf16* __restrict__ P0, const bf16* __restrict__ P1,
    const bf16* __restrict__ Wf, const float* __restrict__ bperm,
    float* __restrict__ ct, bf16* __restrict__ Hout,
    const float* __restrict__ wp, const float* __restrict__ bp,
    float* __restrict__ y, bf16* hst_all)
{
  constexpr int NT = MODE ? NT1 : NT0;

  const int tid = threadIdx.x;
  const int lane = tid & 63, w = tid >> 6;     // w in {0,1}: gate half
  const int lrow = lane & 15, u = lane >> 4;

  f32x4 acc[8][8];
  #pragma unroll
  for (int gf = 0; gf < 8; ++gf)
    #pragma unroll
    for (int bf = 0; bf < 8; ++bf) acc[gf][bf] = (f32x4){0.f, 0.f, 0.f, 0.f};

  // A fragments: per-wave 1KB coalesced chunk per bf (8 b-tiles = full 128 b)
  const int aoff = (u << 7) + (lrow << 3);
  const int BtB = tm >> 4;

  auto loadA = [&](bf16x8 (&af)[8], int kt) {
    #pragma unroll
    for (int bf = 0; bf < 8; ++bf) {
      const bf16* p;
      if constexpr (MODE == 0) {
        p = (kt < 2) ? P0 + ((size_t)((BtB + bf) * 8 + kt * 4) << 7) + aoff
                     : P1 + ((size_t)((BtB + bf) * 128 + (kt - 2) * 4) << 7) + aoff;
      } else {
        p = (kt < 32) ? P0 + ((size_t)((BtB + bf) * 128 + kt * 4) << 7) + aoff
                      : P1 + ((size_t)((BtB + bf) * 128 + (kt - 32) * 4) << 7) + aoff;
      }
      af[bf] = *reinterpret_cast<const bf16x8*>(p);
    }
  };

  // W fragments: [panel][kt][wg][gf][lane][8], wg = w
  const bf16* wfbase = Wf + (size_t)(tn >> 8) * NT * 8192 + w * 4096 + lane * 8;
  auto loadW = [&](bf16x8 (&wf)[8], int kt) {
    const bf16* p = wfbase + (size_t)kt * 8192;
    #pragma unroll
    for (int gf = 0; gf < 8; ++gf)
      wf[gf] = *reinterpret_cast<const bf16x8*>(p + gf * 512);
  };

  bf16x8 afA[8], afB[8], wfA[8], wfB[8];

  loadA(afA, 0); loadW(wfA, 0);
  for (int kt = 0; kt < NT; kt += 2) {
    if (kt + 1 < NT) { loadA(afB, kt + 1); loadW(wfB, kt + 1); }
    SB();
    __builtin_amdgcn_s_setprio(1);
    #pragma unroll
    for (int gf = 0; gf < 8; ++gf)
      #pragma unroll
      for (int bf = 0; bf < 8; ++bf)
        acc[gf][bf] = __builtin_amdgcn_mfma_f32_16x16x32_bf16(wfA[gf], afA[bf], acc[gf][bf], 0, 0, 0);
    __builtin_amdgcn_s_setprio(0);
    if (kt + 2 < NT) { loadA(afA, kt + 2); loadW(wfA, kt + 2); }
    SB();
    __builtin_amdgcn_s_setprio(1);
    #pragma unroll
    for (int gf = 0; gf < 8; ++gf)
      #pragma unroll
      for (int bf = 0; bf < 8; ++bf)
        acc[gf][bf] = __builtin_amdgcn_mfma_f32_16x16x32_bf16(wfB[gf], afB[bf], acc[gf][bf], 0, 0, 0);
    __builtin_amdgcn_s_setprio(0);
  }

  // ---- fused cell epilogue ----
  bf16* hst = hst_all + w * (128 * 36);   // [128 b][36-padded 32 h] bf16
  const int hq = (tn >> 2) + w * 32;      // wave h base (32 h values)
  float yp[8] = {0.f, 0.f, 0.f, 0.f, 0.f, 0.f, 0.f, 0.f};

  // prefetch c (block owns its (h,b) range exclusively)
  float cv[8][8];
  #pragma unroll
  for (int gf = 0; gf < 8; ++gf)
    #pragma unroll
    for (int bf = 0; bf < 8; ++bf)
      cv[gf][bf] = ct[(size_t)(hq + gf * 4 + u) * BB + tm + bf * 16 + lrow];

  #pragma unroll
  for (int gf = 0; gf < 8; ++gf) {
    int hg = hq + gf * 4 + u;
    f32x4 bv = *reinterpret_cast<const f32x4*>(&bperm[hg * 4]);
    float wph = 0.f;
    if constexpr (MODE == 1) wph = wp[hg];
    #pragma unroll
    for (int bf = 0; bf < 8; ++bf) {
      int bg = tm + bf * 16 + lrow;
      float gi = acc[gf][bf][0] + bv[0];
      float gf_ = acc[gf][bf][1] + bv[1];
      float gg = acc[gf][bf][2] + bv[2];
      float go = acc[gf][bf][3] + bv[3];
      float c = cv[gf][bf];
      float cn = sigm(gf_) * c + sigm(gi) * ftanh(gg);
      float hn = sigm(go) * ftanh(cn);
      ct[(size_t)hg * BB + bg] = cn;
      hst[(bf * 16 + lrow) * 36 + gf * 4 + u] = (bf16)hn;
      if constexpr (MODE == 1) yp[bf] += hn * wph;
    }
  }

  asm volatile("s_waitcnt lgkmcnt(0)" ::: "memory");
  SB();

  // H write in fragment layout: wave patch = 128 b x 32 h
  #pragma unroll
  for (int q = 0; q < 8; ++q) {
    int chunk = q * 64 + lane;            // 0..511
    int row = chunk >> 2, seg = chunk & 3;
    bf16x8 v = *reinterpret_cast<const bf16x8*>(&hst[row * 36 + seg * 8]);
    size_t off = ((size_t)((BtB + (row >> 4)) * 128 + (hq >> 3) + seg) << 7)
               + ((row & 15) << 3);
    *reinterpret_cast<bf16x8*>(&Hout[off]) = v;
  }

  if constexpr (MODE == 1) {
    #pragma unroll
    for (int bf = 0; bf < 8; ++bf) {
      float s = yp[bf];
      s += __shfl_xor(s, 16);
      s += __shfl_xor(s, 32);
      if (lane < 16)
        atomicAdd(&y[(size_t)(tm + bf * 16 + lane) * TT + t], s);
    }
  } else {
    if (tn == 0 && tid < 128) y[(size_t)(tm + tid) * TT + t] = bp[0];
  }
}

// Grid 512: bids [0,256) = L2(t); [256,512) = L1(t+1) (CU pairs one of each).
// Decode (XCD-stable panels): x=v&7, r=v>>3: tm=(r&15)*128, tn=(x*2+(r>>4))*256.
__global__ __launch_bounds__(128, 1) void step_kernel(
    const bf16* __restrict__ H1in, const bf16* __restrict__ H2in,
    bf16* __restrict__ H1out, bf16* __restrict__ H2out,
    const bf16* __restrict__ Xf,
    const bf16* __restrict__ Wf0, const bf16* __restrict__ Wf1,
    const float* __restrict__ b0p, const float* __restrict__ b1p,
    float* __restrict__ c1t, float* __restrict__ c2t,
    const float* __restrict__ wp, const float* __restrict__ bp,
    float* __restrict__ y, int t2, int only_l1) {
  __shared__ alignas(16) bf16 hst_all[2 * 128 * 36];   // 18 KB (epilogue only)
  int bid = (int)blockIdx.x;
  if (only_l1 || bid >= 256) {
    int v = only_l1 ? bid : bid - 256;
    int t1 = t2 + 1;
    if (t1 >= TT) return;
    int x = v & 7, r = v >> 3;
    int tm = (r & 15) << 7;
    int tn = ((x << 1) + (r >> 4)) << 8;
    body<0>(tm, tn, t1, Xf + (size_t)t1 * BB * 64, H1in,
            Wf0, b0p, c1t, H1out, nullptr, bp, y, hst_all);
  } else {
    int x = bid & 7, r = bid >> 3;
    int tm = (r & 15) << 7;
    int tn = ((x << 1) + (r >> 4)) << 8;
    body<1>(tm, tn, t2, H1in, H2in,
            Wf1, b1p, c2t, H2out, wp, nullptr, y, hst_all);
  }
}

// ---------------- launch ----------------

extern "C" void kernel_launch(void* const* d_in, const int* in_sizes, int n_in,
                              void* d_out, int out_size, void* d_ws, size_t ws_size,
                              hipStream_t stream) {
  const float* dec   = (const float*)d_in[0];
  const float* ty    = (const float*)d_in[1];
  const float* enc_h = (const float*)d_in[2];
  const float* enc_c = (const float*)d_in[3];
  const float* lec   = (const float*)d_in[4];
  const int*   gid   = (const int*)d_in[5];
  const int*   cp    = (const int*)d_in[6];
  const int*   cct   = (const int*)d_in[7];
  const int*   cpt   = (const int*)d_in[8];
  const int*   ccl   = (const int*)d_in[9];
  const float* gemb  = (const float*)d_in[10];
  const float* ep    = (const float*)d_in[11];
  const float* ect   = (const float*)d_in[12];
  const float* ept   = (const float*)d_in[13];
  const float* ecl   = (const float*)d_in[14];
  const float* Wih0  = (const float*)d_in[15];
  const float* Whh0  = (const float*)d_in[16];
  const float* b0    = (const float*)d_in[17];
  const float* Wih1  = (const float*)d_in[18];
  const float* Whh1  = (const float*)d_in[19];
  const float* b1    = (const float*)d_in[20];
  const float* wp    = (const float*)d_in[21];
  const float* bp    = (const float*)d_in[22];
  float* y = (float*)d_out;

  char* ws = (char*)d_ws;
  bf16* Wf1   = (bf16*)ws;  ws += (size_t)16 * NT1 * 8192 * 2;  // 16.8 MB
  bf16* Wf0   = (bf16*)ws;  ws += (size_t)16 * NT0 * 8192 * 2;  //  8.9 MB
  bf16* Xf    = (bf16*)ws;  ws += (size_t)BB * TT * 64 * 2;     // 25.2 MB
  bf16* H1a   = (bf16*)ws;  ws += (size_t)BB * 1024 * 2;        //  4.2 MB each
  bf16* H1b   = (bf16*)ws;  ws += (size_t)BB * 1024 * 2;
  bf16* H2a   = (bf16*)ws;  ws += (size_t)BB * 1024 * 2;
  bf16* H2b   = (bf16*)ws;  ws += (size_t)BB * 1024 * 2;
  float* c1t  = (float*)ws; ws += (size_t)BB * 1024 * 4;        //  8.4 MB
  float* c2t  = (float*)ws; ws += (size_t)BB * 1024 * 4;        //  8.4 MB
  float* b0p  = (float*)ws; ws += (size_t)NG * 4;
  float* b1p  = (float*)ws; ws += (size_t)NG * 4;

  build_wf1<<<(16 * NT1 * 8192) / 256, 256, 0, stream>>>(Wih1, Whh1, Wf1);
  build_wf0<<<(16 * NT0 * 8192 + 255) / 256, 256, 0, stream>>>(Wih0, Whh0, Wf0);
  perm_bias<<<NG / 256, 256, 0, stream>>>(b0, b1, b0p, b1p);
  build_xf<<<(BB * TT + 255) / 256, 256, 0, stream>>>(dec, ty, lec, gid, cp, cct, cpt, ccl,
                                                      gemb, ep, ect, ept, ecl, Xf);
  init_state<<<(BB * 1024) / 256, 256, 0, stream>>>(enc_h, enc_c, H1b, H2b, c1t, c2t);

  // prologue: L1(0) alone (grid 256). h1(t) in H1[t&1]; h2(t) in H2[t&1].
  step_kernel<<<256, 128, 0, stream>>>(H1b, nullptr, H1a, nullptr, Xf, Wf0, Wf1,
                                       b0p, b1p, c1t, c2t, wp, bp, y, -1, 1);
  for (int t = 0; t < TT; ++t) {
    bf16* h1i = (t & 1) ? H1b : H1a;
    bf16* h1o = (t & 1) ? H1a : H1b;
    bf16* h2i = (t & 1) ? H2a : H2b;
    bf16* h2o = (t & 1) ? H2b : H2a;
    step_kernel<<<512, 128, 0, stream>>>(h1i, h2i, h1o, h2o, Xf, Wf0, Wf1,
                                         b0p, b1p, c1t, c2t, wp, bp, y, t, 0);
  }
}

// Round 16
// 6009.441 us; speedup vs baseline: 1.9940x; 1.9940x over previous
//
#include <hip/hip_runtime.h>
#include <hip/hip_bf16.h>
#include <stdint.h>

// Decoder: 2-layer LSTM, B=2048, T=96, H=1024, teacher forcing=1.0.
// Round 16: R14 champion + hst pad 32->36 (kills the 16-way transpose bank
// conflict; R15-verified 0 conflicts) + W-first load issue. K-loop and
// register budget byte-identical to R14 (acc 128 AGPR + 128 VGPR = exactly
// 2 waves/SIMD). Grid 512 = 256 L2 + 256 L1 paired per CU.

#define BB  2048
#define TT  96
#define NG  4096
#define NT0 34        // L1 K-iters (K=1088 = 2x32 x-part + 32x32 h-part)
#define NT1 64        // L2 K-iters (K=2048)

typedef __bf16 bf16;
typedef __bf16 bf16x8 __attribute__((ext_vector_type(8)));
typedef float  f32x4  __attribute__((ext_vector_type(4)));

__device__ __forceinline__ float sigm(float x) { return 1.0f / (1.0f + __expf(-x)); }
__device__ __forceinline__ float ftanh(float x) { return 2.0f / (1.0f + __expf(-2.0f * x)) - 1.0f; }

#define SB() __builtin_amdgcn_sched_barrier(0)

// ---------------- prep kernels ----------------
// Gate-interleaved n' = h*4 + gate (orig row n = (n'&3)*1024 + (n'>>2)).
// Wfrag: [panel(256g)][kt][wg(2)][gf(8)][lane(64)][j(8)].
// Afrag (H, X): tile (b>>4, k>>3) of 16x8 stored contiguous 128 elems:
//   off = ((b>>4)*K8 + (k>>3))*128 + (b&15)*8 + (k&7);  K8 = 128 (H), 8 (X).

__global__ __launch_bounds__(256) void build_wf1(const float* __restrict__ Wih1,
                                                 const float* __restrict__ Whh1,
                                                 bf16* __restrict__ Wf) {
  int idx = blockIdx.x * 256 + threadIdx.x;      // 16*64*8192
  if (idx >= 16 * NT1 * 8192) return;
  int j = idx & 7, lane = (idx >> 3) & 63, gf = (idx >> 9) & 7;
  int wg = (idx >> 12) & 1, kt = (idx >> 13) & 63, panel = idx >> 19;
  int np = panel * 256 + wg * 128 + gf * 16 + (lane & 15);
  int k  = kt * 32 + ((lane >> 4) << 3) + j;
  int n  = (np & 3) * 1024 + (np >> 2);
  float v = (k < 1024) ? Wih1[n * 1024 + k] : Whh1[n * 1024 + (k - 1024)];
  Wf[idx] = (bf16)v;
}

__global__ __launch_bounds__(256) void build_wf0(const float* __restrict__ Wih0,
                                                 const float* __restrict__ Whh0,
                                                 bf16* __restrict__ Wf) {
  int idx = blockIdx.x * 256 + threadIdx.x;      // 16*34*8192
  if (idx >= 16 * NT0 * 8192) return;
  int j = idx & 7, lane = (idx >> 3) & 63, gf = (idx >> 9) & 7;
  int wg = (idx >> 12) & 1;
  int rem = idx >> 13;
  int kt = rem % NT0, panel = rem / NT0;
  int np = panel * 256 + wg * 128 + gf * 16 + (lane & 15);
  int k  = kt * 32 + ((lane >> 4) << 3) + j;
  int n  = (np & 3) * 1024 + (np >> 2);
  float v;
  if (k < 60)      v = Wih0[n * 60 + k];
  else if (k < 64) v = 0.0f;
  else             v = Whh0[n * 1024 + (k - 64)];
  Wf[idx] = (bf16)v;
}

__global__ __launch_bounds__(256) void perm_bias(const float* __restrict__ b0,
                                                 const float* __restrict__ b1,
                                                 float* __restrict__ b0p,
                                                 float* __restrict__ b1p) {
  int idx = blockIdx.x * 256 + threadIdx.x;
  if (idx >= NG) return;
  int n = (idx & 3) * 1024 + (idx >> 2);
  b0p[idx] = b0[n];
  b1p[idx] = b1[n];
}

// Xf: per-t slab of 2048*64 elems, 16x8-tiled (K8 = 8)
__global__ __launch_bounds__(256) void build_xf(
    const float* __restrict__ dec, const float* __restrict__ ty, const float* __restrict__ lec,
    const int* __restrict__ gid, const int* __restrict__ cp, const int* __restrict__ cct,
    const int* __restrict__ cpt, const int* __restrict__ ccl,
    const float* __restrict__ gemb, const float* __restrict__ ep, const float* __restrict__ ect,
    const float* __restrict__ ept, const float* __restrict__ ecl,
    bf16* __restrict__ Xf) {
  int idx = blockIdx.x * 256 + threadIdx.x;  // over B*T
  if (idx >= BB * TT) return;
  int b = idx / TT, t = idx % TT;
  float xv[64];
  xv[0] = (t == 0) ? lec[b] : ty[b * TT + t - 1];
  const float* d = dec + (size_t)idx * 32;
  #pragma unroll
  for (int k = 0; k < 32; ++k) xv[1 + k] = d[k];
  const float* e;
  e = ep  + cp[b]  * 4;  for (int j = 0; j < 4;  ++j) xv[33 + j] = e[j];
  e = ect + cct[b] * 2;  for (int j = 0; j < 2;  ++j) xv[37 + j] = e[j];
  e = ept + cpt[b] * 3;  for (int j = 0; j < 3;  ++j) xv[39 + j] = e[j];
  e = ecl + ccl[b] * 2;  for (int j = 0; j < 2;  ++j) xv[42 + j] = e[j];
  e = gemb + gid[b] * 16; for (int j = 0; j < 16; ++j) xv[44 + j] = e[j];
  for (int j = 60; j < 64; ++j) xv[j] = 0.0f;
  bf16* slab = Xf + (size_t)t * BB * 64;
  int bt = b >> 4, bl = b & 15;
  #pragma unroll
  for (int k = 0; k < 64; ++k)
    slab[((size_t)(bt * 8 + (k >> 3)) << 7) + bl * 8 + (k & 7)] = (bf16)xv[k];
}

// enc state -> Hf fragment layout (K8=128) + transposed c ([h][b])
__global__ __launch_bounds__(256) void init_state(const float* __restrict__ enc_h,
                                                  const float* __restrict__ enc_c,
                                                  bf16* __restrict__ H1b,
                                                  bf16* __restrict__ H2b,
                                                  float* __restrict__ c1t,
                                                  float* __restrict__ c2t) {
  int idx = blockIdx.x * 256 + threadIdx.x;  // over B*H
  if (idx >= BB * 1024) return;
  int b = idx >> 10, h = idx & 1023;
  size_t off = ((size_t)((b >> 4) * 128 + (h >> 3)) << 7) + ((b & 15) << 3) + (h & 7);
  H1b[off] = (bf16)enc_h[idx];
  H2b[off] = (bf16)enc_h[(size_t)BB * 1024 + idx];
  c1t[(size_t)h * BB + b] = enc_c[idx];
  c2t[(size_t)h * BB + b] = enc_c[(size_t)BB * 1024 + idx];
}

// ---------------- streaming GEMM + fused cell: 128b x 256g, 4 waves --------
// gates(b,n') = A(b,:).W(n',:). mfma(wf, af): lane's f32x4 = {i,f,g,o} of one
// (b,h) cell: h = (tn>>2) + wg*32 + gf*4 + u, b = tm + wb*64 + bf*16 + l15.
// Both operands stream global->reg (L2/L3-resident), no LDS/barriers in loop.

template <int MODE>
__device__ __forceinline__ void body(
    int tm, int tn, int t,
    const bf16* __restrict__ P0, const bf16* __restrict__ P1,
    const bf16* __restrict__ Wf, const float* __restrict__ bperm,
    float* __restrict__ ct, bf16* __restrict__ Hout,
    const float* __restrict__ wp, const float* __restrict__ bp,
    float* __restrict__ y, bf16* hst_all)
{
  constexpr int NT = MODE ? NT1 : NT0;

  const int tid = threadIdx.x;
  const int lane = tid & 63, w = tid >> 6;
  const int lrow = lane & 15, u = lane >> 4;
  const int wb = w & 1, wg = w >> 1;

  f32x4 acc[8][4];
  #pragma unroll
  for (int gf = 0; gf < 8; ++gf)
    #pragma unroll
    for (int bf = 0; bf < 4; ++bf) acc[gf][bf] = (f32x4){0.f, 0.f, 0.f, 0.f};

  // A fragments: per-wave 1KB coalesced chunk per bf
  const int aoff = (u << 7) + (lrow << 3);       // lane offset within 512-elem chunk
  const int BtB = (tm >> 4) + wb * 4;            // base b-tile

  auto loadA = [&](bf16x8 (&af)[4], int kt) {
    #pragma unroll
    for (int bf = 0; bf < 4; ++bf) {
      const bf16* p;
      if constexpr (MODE == 0) {
        p = (kt < 2) ? P0 + ((size_t)((BtB + bf) * 8 + kt * 4) << 7) + aoff
                     : P1 + ((size_t)((BtB + bf) * 128 + (kt - 2) * 4) << 7) + aoff;
      } else {
        p = (kt < 32) ? P0 + ((size_t)((BtB + bf) * 128 + kt * 4) << 7) + aoff
                      : P1 + ((size_t)((BtB + bf) * 128 + (kt - 32) * 4) << 7) + aoff;
      }
      af[bf] = *reinterpret_cast<const bf16x8*>(p);
    }
  };

  // W fragments: [panel][kt][wg][gf][lane][8]
  const bf16* wfbase = Wf + (size_t)(tn >> 8) * NT * 8192 + wg * 4096 + lane * 8;
  auto loadW = [&](bf16x8 (&wf)[8], int kt) {
    const bf16* p = wfbase + (size_t)kt * 8192;
    #pragma unroll
    for (int gf = 0; gf < 8; ++gf)
      wf[gf] = *reinterpret_cast<const bf16x8*>(p + gf * 512);
  };

  bf16x8 afA[4], afB[4], wfA[8], wfB[8];

  loadW(wfA, 0); loadA(afA, 0);
  for (int kt = 0; kt < NT; kt += 2) {
    if (kt + 1 < NT) { loadW(wfB, kt + 1); loadA(afB, kt + 1); }
    SB();
    __builtin_amdgcn_s_setprio(1);
    #pragma unroll
    for (int gf = 0; gf < 8; ++gf)
      #pragma unroll
      for (int bf = 0; bf < 4; ++bf)
        acc[gf][bf] = __builtin_amdgcn_mfma_f32_16x16x32_bf16(wfA[gf], afA[bf], acc[gf][bf], 0, 0, 0);
    __builtin_amdgcn_s_setprio(0);
    if (kt + 2 < NT) { loadW(wfA, kt + 2); loadA(afA, kt + 2); }
    SB();
    __builtin_amdgcn_s_setprio(1);
    #pragma unroll
    for (int gf = 0; gf < 8; ++gf)
      #pragma unroll
      for (int bf = 0; bf < 4; ++bf)
        acc[gf][bf] = __builtin_amdgcn_mfma_f32_16x16x32_bf16(wfB[gf], afB[bf], acc[gf][bf], 0, 0, 0);
    __builtin_amdgcn_s_setprio(0);
  }

  // ---- fused cell epilogue (per-wave private LDS transpose; no barriers) ----
  // hst stride 36 (72B): 16-bank-step conflict of stride 32 eliminated (R15: 0 conflicts).
  bf16* hst = hst_all + w * 2304;       // [64 b][36-padded 32 h] bf16
  const int hq = (tn >> 2) + wg * 32;   // wave h base (32 h values)
  const int bgb = tm + wb * 64;         // wave batch base (64 rows)
  float yp[4] = {0.f, 0.f, 0.f, 0.f};

  #pragma unroll
  for (int gf = 0; gf < 8; ++gf) {
    int hg = hq + gf * 4 + u;
    f32x4 bv = *reinterpret_cast<const f32x4*>(&bperm[hg * 4]);
    float wph = 0.f;
    if constexpr (MODE == 1) wph = wp[hg];
    #pragma unroll
    for (int bf = 0; bf < 4; ++bf) {
      int bg = bgb + bf * 16 + lrow;
      float gi = acc[gf][bf][0] + bv[0];
      float gf_ = acc[gf][bf][1] + bv[1];
      float gg = acc[gf][bf][2] + bv[2];
      float go = acc[gf][bf][3] + bv[3];
      float* cp_ = ct + (size_t)hg * BB + bg;
      float c = *cp_;
      float cn = sigm(gf_) * c + sigm(gi) * ftanh(gg);
      float hn = sigm(go) * ftanh(cn);
      *cp_ = cn;
      hst[(bf * 16 + lrow) * 36 + gf * 4 + u] = (bf16)hn;
      if constexpr (MODE == 1) yp[bf] += hn * wph;
    }
  }

  asm volatile("s_waitcnt lgkmcnt(0)" ::: "memory");
  SB();

  // H write in fragment layout: chunk row=b_local (0..63), seg = 8-h group.
  #pragma unroll
  for (int q = 0; q < 4; ++q) {
    int chunk = q * 64 + lane;          // 0..255
    int row = chunk >> 2, seg = chunk & 3;
    bf16x8 v = *reinterpret_cast<const bf16x8*>(&hst[row * 36 + seg * 8]);
    size_t off = ((size_t)(((bgb >> 4) + (row >> 4)) * 128 + (hq >> 3) + seg) << 7)
               + ((row & 15) << 3);
    *reinterpret_cast<bf16x8*>(&Hout[off]) = v;
  }

  if constexpr (MODE == 1) {
    #pragma unroll
    for (int bf = 0; bf < 4; ++bf) {
      float s = yp[bf];
      s += __shfl_xor(s, 16);
      s += __shfl_xor(s, 32);
      if (lane < 16)
        atomicAdd(&y[(size_t)(bgb + bf * 16 + lane) * TT + t], s);
    }
  } else {
    if (tn == 0 && tid < 128) y[(size_t)(tm + tid) * TT + t] = bp[0];
  }
}

// Grid 512: bids [0,256) = L2(t); [256,512) = L1(t+1) (CU pairs one of each).
// Decode (XCD-stable panels): x=v&7, r=v>>3: tm=(r&15)*128, tn=(x*2+(r>>4))*256.
__global__ __launch_bounds__(256, 2) void step_kernel(
    const bf16* __restrict__ H1in, const bf16* __restrict__ H2in,
    bf16* __restrict__ H1out, bf16* __restrict__ H2out,
    const bf16* __restrict__ Xf,
    const bf16* __restrict__ Wf0, const bf16* __restrict__ Wf1,
    const float* __restrict__ b0p, const float* __restrict__ b1p,
    float* __restrict__ c1t, float* __restrict__ c2t,
    const float* __restrict__ wp, const float* __restrict__ bp,
    float* __restrict__ y, int t2, int only_l1) {
  __shared__ alignas(16) bf16 hst_all[4 * 2304];   // 18 KB (epilogue only)
  int bid = (int)blockIdx.x;
  if (only_l1 || bid >= 256) {
    int v = only_l1 ? bid : bid - 256;
    int t1 = t2 + 1;
    if (t1 >= TT) return;
    int x = v & 7, r = v >> 3;
    int tm = (r & 15) << 7;
    int tn = ((x << 1) + (r >> 4)) << 8;
    body<0>(tm, tn, t1, Xf + (size_t)t1 * BB * 64, H1in,
            Wf0, b0p, c1t, H1out, nullptr, bp, y, hst_all);
  } else {
    int x = bid & 7, r = bid >> 3;
    int tm = (r & 15) << 7;
    int tn = ((x << 1) + (r >> 4)) << 8;
    body<1>(tm, tn, t2, H1in, H2in,
            Wf1, b1p, c2t, H2out, wp, nullptr, y, hst_all);
  }
}

// ---------------- launch ----------------

extern "C" void kernel_launch(void* const* d_in, const int* in_sizes, int n_in,
                              void* d_out, int out_size, void* d_ws, size_t ws_size,
                              hipStream_t stream) {
  const float* dec   = (const float*)d_in[0];
  const float* ty    = (const float*)d_in[1];
  const float* enc_h = (const float*)d_in[2];
  const float* enc_c = (const float*)d_in[3];
  const float* lec   = (const float*)d_in[4];
  const int*   gid   = (const int*)d_in[5];
  const int*   cp    = (const int*)d_in[6];
  const int*   cct   = (const int*)d_in[7];
  const int*   cpt   = (const int*)d_in[8];
  const int*   ccl   = (const int*)d_in[9];
  const float* gemb  = (const float*)d_in[10];
  const float* ep    = (const float*)d_in[11];
  const float* ect   = (const float*)d_in[12];
  const float* ept   = (const float*)d_in[13];
  const float* ecl   = (const float*)d_in[14];
  const float* Wih0  = (const float*)d_in[15];
  const float* Whh0  = (const float*)d_in[16];
  const float* b0    = (const float*)d_in[17];
  const float* Wih1  = (const float*)d_in[18];
  const float* Whh1  = (const float*)d_in[19];
  const float* b1    = (const float*)d_in[20];
  const float* wp    = (const float*)d_in[21];
  const float* bp    = (const float*)d_in[22];
  float* y = (float*)d_out;

  char* ws = (char*)d_ws;
  bf16* Wf1   = (bf16*)ws;  ws += (size_t)16 * NT1 * 8192 * 2;  // 16.8 MB
  bf16* Wf0   = (bf16*)ws;  ws += (size_t)16 * NT0 * 8192 * 2;  //  8.9 MB
  bf16* Xf    = (bf16*)ws;  ws += (size_t)BB * TT * 64 * 2;     // 25.2 MB
  bf16* H1a   = (bf16*)ws;  ws += (size_t)BB * 1024 * 2;        //  4.2 MB each
  bf16* H1b   = (bf16*)ws;  ws += (size_t)BB * 1024 * 2;
  bf16* H2a   = (bf16*)ws;  ws += (size_t)BB * 1024 * 2;
  bf16* H2b   = (bf16*)ws;  ws += (size_t)BB * 1024 * 2;
  float* c1t  = (float*)ws; ws += (size_t)BB * 1024 * 4;        //  8.4 MB
  float* c2t  = (float*)ws; ws += (size_t)BB * 1024 * 4;        //  8.4 MB
  float* b0p  = (float*)ws; ws += (size_t)NG * 4;
  float* b1p  = (float*)ws; ws += (size_t)NG * 4;

  build_wf1<<<(16 * NT1 * 8192) / 256, 256, 0, stream>>>(Wih1, Whh1, Wf1);
  build_wf0<<<(16 * NT0 * 8192 + 255) / 256, 256, 0, stream>>>(Wih0, Whh0, Wf0);
  perm_bias<<<NG / 256, 256, 0, stream>>>(b0, b1, b0p, b1p);
  build_xf<<<(BB * TT + 255) / 256, 256, 0, stream>>>(dec, ty, lec, gid, cp, cct, cpt, ccl,
                                                      gemb, ep, ect, ept, ecl, Xf);
  init_state<<<(BB * 1024) / 256, 256, 0, stream>>>(enc_h, enc_c, H1b, H2b, c1t, c2t);

  // prologue: L1(0) alone (grid 256). h1(t) in H1[t&1]; h2(t) in H2[t&1].
  step_kernel<<<256, 256, 0, stream>>>(H1b, nullptr, H1a, nullptr, Xf, Wf0, Wf1,
                                       b0p, b1p, c1t, c2t, wp, bp, y, -1, 1);
  for (int t = 0; t < TT; ++t) {
    bf16* h1i = (t & 1) ? H1b : H1a;
    bf16* h1o = (t & 1) ? H1a : H1b;
    bf16* h2i = (t & 1) ? H2a : H2b;
    bf16* h2o = (t & 1) ? H2b : H2a;
    step_kernel<<<512, 256, 0, stream>>>(h1i, h2i, h1o, h2o, Xf, Wf0, Wf1,
                                         b0p, b1p, c1t, c2t, wp, bp, y, t, 0);
  }
}

// Round 17
// 6005.709 us; speedup vs baseline: 1.9952x; 1.0006x over previous
//
#include <hip/hip_runtime.h>
#include <hip/hip_bf16.h>
#include <stdint.h>

// Decoder: 2-layer LSTM, B=2048, T=96, H=1024, teacher forcing=1.0.
// Round 16: R14 champion + hst pad 32->36 (kills the 16-way transpose bank
// conflict; R15-verified 0 conflicts) + W-first load issue. K-loop and
// register budget byte-identical to R14 (acc 128 AGPR + 128 VGPR = exactly
// 2 waves/SIMD). Grid 512 = 256 L2 + 256 L1 paired per CU.

#define BB  2048
#define TT  96
#define NG  4096
#define NT0 34        // L1 K-iters (K=1088 = 2x32 x-part + 32x32 h-part)
#define NT1 64        // L2 K-iters (K=2048)

typedef __bf16 bf16;
typedef __bf16 bf16x8 __attribute__((ext_vector_type(8)));
typedef float  f32x4  __attribute__((ext_vector_type(4)));

__device__ __forceinline__ float sigm(float x) { return 1.0f / (1.0f + __expf(-x)); }
__device__ __forceinline__ float ftanh(float x) { return 2.0f / (1.0f + __expf(-2.0f * x)) - 1.0f; }

#define SB() __builtin_amdgcn_sched_barrier(0)

// ---------------- prep kernels ----------------
// Gate-interleaved n' = h*4 + gate (orig row n = (n'&3)*1024 + (n'>>2)).
// Wfrag: [panel(256g)][kt][wg(2)][gf(8)][lane(64)][j(8)].
// Afrag (H, X): tile (b>>4, k>>3) of 16x8 stored contiguous 128 elems:
//   off = ((b>>4)*K8 + (k>>3))*128 + (b&15)*8 + (k&7);  K8 = 128 (H), 8 (X).

__global__ __launch_bounds__(256) void build_wf1(const float* __restrict__ Wih1,
                                                 const float* __restrict__ Whh1,
                                                 bf16* __restrict__ Wf) {
  int idx = blockIdx.x * 256 + threadIdx.x;      // 16*64*8192
  if (idx >= 16 * NT1 * 8192) return;
  int j = idx & 7, lane = (idx >> 3) & 63, gf = (idx >> 9) & 7;
  int wg = (idx >> 12) & 1, kt = (idx >> 13) & 63, panel = idx >> 19;
  int np = panel * 256 + wg * 128 + gf * 16 + (lane & 15);
  int k  = kt * 32 + ((lane >> 4) << 3) + j;
  int n  = (np & 3) * 1024 + (np >> 2);
  float v = (k < 1024) ? Wih1[n * 1024 + k] : Whh1[n * 1024 + (k - 1024)];
  Wf[idx] = (bf16)v;
}

__global__ __launch_bounds__(256) void build_wf0(const float* __restrict__ Wih0,
                                                 const float* __restrict__ Whh0,
                                                 bf16* __restrict__ Wf) {
  int idx = blockIdx.x * 256 + threadIdx.x;      // 16*34*8192
  if (idx >= 16 * NT0 * 8192) return;
  int j = idx & 7, lane = (idx >> 3) & 63, gf = (idx >> 9) & 7;
  int wg = (idx >> 12) & 1;
  int rem = idx >> 13;
  int kt = rem % NT0, panel = rem / NT0;
  int np = panel * 256 + wg * 128 + gf * 16 + (lane & 15);
  int k  = kt * 32 + ((lane >> 4) << 3) + j;
  int n  = (np & 3) * 1024 + (np >> 2);
  float v;
  if (k < 60)      v = Wih0[n * 60 + k];
  else if (k < 64) v = 0.0f;
  else             v = Whh0[n * 1024 + (k - 64)];
  Wf[idx] = (bf16)v;
}

__global__ __launch_bounds__(256) void perm_bias(const float* __restrict__ b0,
                                                 const float* __restrict__ b1,
                                                 float* __restrict__ b0p,
                                                 float* __restrict__ b1p) {
  int idx = blockIdx.x * 256 + threadIdx.x;
  if (idx >= NG) return;
  int n = (idx & 3) * 1024 + (idx >> 2);
  b0p[idx] = b0[n];
  b1p[idx] = b1[n];
}

// Xf: per-t slab of 2048*64 elems, 16x8-tiled (K8 = 8)
__global__ __launch_bounds__(256) void build_xf(
    const float* __restrict__ dec, const float* __restrict__ ty, const float* __restrict__ lec,
    const int* __restrict__ gid, const int* __restrict__ cp, const int* __restrict__ cct,
    const int* __restrict__ cpt, const int* __restrict__ ccl,
    const float* __restrict__ gemb, const float* __restrict__ ep, const float* __restrict__ ect,
    const float* __restrict__ ept, const float* __restrict__ ecl,
    bf16* __restrict__ Xf) {
  int idx = blockIdx.x * 256 + threadIdx.x;  // over B*T
  if (idx >= BB * TT) return;
  int b = idx / TT, t = idx % TT;
  float xv[64];
  xv[0] = (t == 0) ? lec[b] : ty[b * TT + t - 1];
  const float* d = dec + (size_t)idx * 32;
  #pragma unroll
  for (int k = 0; k < 32; ++k) xv[1 + k] = d[k];
  const float* e;
  e = ep  + cp[b]  * 4;  for (int j = 0; j < 4;  ++j) xv[33 + j] = e[j];
  e = ect + cct[b] * 2;  for (int j = 0; j < 2;  ++j) xv[37 + j] = e[j];
  e = ept + cpt[b] * 3;  for (int j = 0; j < 3;  ++j) xv[39 + j] = e[j];
  e = ecl + ccl[b] * 2;  for (int j = 0; j < 2;  ++j) xv[42 + j] = e[j];
  e = gemb + gid[b] * 16; for (int j = 0; j < 16; ++j) xv[44 + j] = e[j];
  for (int j = 60; j < 64; ++j) xv[j] = 0.0f;
  bf16* slab = Xf + (size_t)t * BB * 64;
  int bt = b >> 4, bl = b & 15;
  #pragma unroll
  for (int k = 0; k < 64; ++k)
    slab[((size_t)(bt * 8 + (k >> 3)) << 7) + bl * 8 + (k & 7)] = (bf16)xv[k];
}

// enc state -> Hf fragment layout (K8=128) + transposed c ([h][b])
__global__ __launch_bounds__(256) void init_state(const float* __restrict__ enc_h,
                                                  const float* __restrict__ enc_c,
                                                  bf16* __restrict__ H1b,
                                                  bf16* __restrict__ H2b,
                                                  float* __restrict__ c1t,
                                                  float* __restrict__ c2t) {
  int idx = blockIdx.x * 256 + threadIdx.x;  // over B*H
  if (idx >= BB * 1024) return;
  int b = idx >> 10, h = idx & 1023;
  size_t off = ((size_t)((b >> 4) * 128 + (h >> 3)) << 7) + ((b & 15) << 3) + (h & 7);
  H1b[off] = (bf16)enc_h[idx];
  H2b[off] = (bf16)enc_h[(size_t)BB * 1024 + idx];
  c1t[(size_t)h * BB + b] = enc_c[idx];
  c2t[(size_t)h * BB + b] = enc_c[(size_t)BB * 1024 + idx];
}

// ---------------- streaming GEMM + fused cell: 128b x 256g, 4 waves --------
// gates(b,n') = A(b,:).W(n',:). mfma(wf, af): lane's f32x4 = {i,f,g,o} of one
// (b,h) cell: h = (tn>>2) + wg*32 + gf*4 + u, b = tm + wb*64 + bf*16 + l15.
// Both operands stream global->reg (L2/L3-resident), no LDS/barriers in loop.

template <int MODE>
__device__ __forceinline__ void body(
    int tm, int tn, int t,
    const bf16* __restrict__ P0, const bf16* __restrict__ P1,
    const bf16* __restrict__ Wf, const float* __restrict__ bperm,
    float* __restrict__ ct, bf16* __restrict__ Hout,
    const float* __restrict__ wp, const float* __restrict__ bp,
    float* __restrict__ y, bf16* hst_all)
{
  constexpr int NT = MODE ? NT1 : NT0;

  const int tid = threadIdx.x;
  const int lane = tid & 63, w = tid >> 6;
  const int lrow = lane & 15, u = lane >> 4;
  const int wb = w & 1, wg = w >> 1;

  f32x4 acc[8][4];
  #pragma unroll
  for (int gf = 0; gf < 8; ++gf)
    #pragma unroll
    for (int bf = 0; bf < 4; ++bf) acc[gf][bf] = (f32x4){0.f, 0.f, 0.f, 0.f};

  // A fragments: per-wave 1KB coalesced chunk per bf
  const int aoff = (u << 7) + (lrow << 3);       // lane offset within 512-elem chunk
  const int BtB = (tm >> 4) + wb * 4;            // base b-tile

  auto loadA = [&](bf16x8 (&af)[4], int kt) {
    #pragma unroll
    for (int bf = 0; bf < 4; ++bf) {
      const bf16* p;
      if constexpr (MODE == 0) {
        p = (kt < 2) ? P0 + ((size_t)((BtB + bf) * 8 + kt * 4) << 7) + aoff
                     : P1 + ((size_t)((BtB + bf) * 128 + (kt - 2) * 4) << 7) + aoff;
      } else {
        p = (kt < 32) ? P0 + ((size_t)((BtB + bf) * 128 + kt * 4) << 7) + aoff
                      : P1 + ((size_t)((BtB + bf) * 128 + (kt - 32) * 4) << 7) + aoff;
      }
      af[bf] = *reinterpret_cast<const bf16x8*>(p);
    }
  };

  // W fragments: [panel][kt][wg][gf][lane][8]
  const bf16* wfbase = Wf + (size_t)(tn >> 8) * NT * 8192 + wg * 4096 + lane * 8;
  auto loadW = [&](bf16x8 (&wf)[8], int kt) {
    const bf16* p = wfbase + (size_t)kt * 8192;
    #pragma unroll
    for (int gf = 0; gf < 8; ++gf)
      wf[gf] = *reinterpret_cast<const bf16x8*>(p + gf * 512);
  };

  bf16x8 afA[4], afB[4], wfA[8], wfB[8];

  loadW(wfA, 0); loadA(afA, 0);
  for (int kt = 0; kt < NT; kt += 2) {
    if (kt + 1 < NT) { loadW(wfB, kt + 1); loadA(afB, kt + 1); }
    SB();
    __builtin_amdgcn_s_setprio(1);
    #pragma unroll
    for (int gf = 0; gf < 8; ++gf)
      #pragma unroll
      for (int bf = 0; bf < 4; ++bf)
        acc[gf][bf] = __builtin_amdgcn_mfma_f32_16x16x32_bf16(wfA[gf], afA[bf], acc[gf][bf], 0, 0, 0);
    __builtin_amdgcn_s_setprio(0);
    if (kt + 2 < NT) { loadW(wfA, kt + 2); loadA(afA, kt + 2); }
    SB();
    __builtin_amdgcn_s_setprio(1);
    #pragma unroll
    for (int gf = 0; gf < 8; ++gf)
      #pragma unroll
      for (int bf = 0; bf < 4; ++bf)
        acc[gf][bf] = __builtin_amdgcn_mfma_f32_16x16x32_bf16(wfB[gf], afB[bf], acc[gf][bf], 0, 0, 0);
    __builtin_amdgcn_s_setprio(0);
  }

  // ---- fused cell epilogue (per-wave private LDS transpose; no barriers) ----
  // hst stride 36 (72B): 16-bank-step conflict of stride 32 eliminated (R15: 0 conflicts).
  bf16* hst = hst_all + w * 2304;       // [64 b][36-padded 32 h] bf16
  const int hq = (tn >> 2) + wg * 32;   // wave h base (32 h values)
  const int bgb = tm + wb * 64;         // wave batch base (64 rows)
  float yp[4] = {0.f, 0.f, 0.f, 0.f};

  #pragma unroll
  for (int gf = 0; gf < 8; ++gf) {
    int hg = hq + gf * 4 + u;
    f32x4 bv = *reinterpret_cast<const f32x4*>(&bperm[hg * 4]);
    float wph = 0.f;
    if constexpr (MODE == 1) wph = wp[hg];
    #pragma unroll
    for (int bf = 0; bf < 4; ++bf) {
      int bg = bgb + bf * 16 + lrow;
      float gi = acc[gf][bf][0] + bv[0];
      float gf_ = acc[gf][bf][1] + bv[1];
      float gg = acc[gf][bf][2] + bv[2];
      float go = acc[gf][bf][3] + bv[3];
      float* cp_ = ct + (size_t)hg * BB + bg;
      float c = *cp_;
      float cn = sigm(gf_) * c + sigm(gi) * ftanh(gg);
      float hn = sigm(go) * ftanh(cn);
      *cp_ = cn;
      hst[(bf * 16 + lrow) * 36 + gf * 4 + u] = (bf16)hn;
      if constexpr (MODE == 1) yp[bf] += hn * wph;
    }
  }

  asm volatile("s_waitcnt lgkmcnt(0)" ::: "memory");
  SB();

  // H write in fragment layout: chunk row=b_local (0..63), seg = 8-h group.
  #pragma unroll
  for (int q = 0; q < 4; ++q) {
    int chunk = q * 64 + lane;          // 0..255
    int row = chunk >> 2, seg = chunk & 3;
    bf16x8 v = *reinterpret_cast<const bf16x8*>(&hst[row * 36 + seg * 8]);
    size_t off = ((size_t)(((bgb >> 4) + (row >> 4)) * 128 + (hq >> 3) + seg) << 7)
               + ((row & 15) << 3);
    *reinterpret_cast<bf16x8*>(&Hout[off]) = v;
  }

  if constexpr (MODE == 1) {
    #pragma unroll
    for (int bf = 0; bf < 4; ++bf) {
      float s = yp[bf];
      s += __shfl_xor(s, 16);
      s += __shfl_xor(s, 32);
      if (lane < 16)
        atomicAdd(&y[(size_t)(bgb + bf * 16 + lane) * TT + t], s);
    }
  } else {
    if (tn == 0 && tid < 128) y[(size_t)(tm + tid) * TT + t] = bp[0];
  }
}

// Grid 512: bids [0,256) = L2(t); [256,512) = L1(t+1) (CU pairs one of each).
// Decode (XCD-stable panels): x=v&7, r=v>>3: tm=(r&15)*128, tn=(x*2+(r>>4))*256.
__global__ __launch_bounds__(256, 2) void step_kernel(
    const bf16* __restrict__ H1in, const bf16* __restrict__ H2in,
    bf16* __restrict__ H1out, bf16* __restrict__ H2out,
    const bf16* __restrict__ Xf,
    const bf16* __restrict__ Wf0, const bf16* __restrict__ Wf1,
    const float* __restrict__ b0p, const float* __restrict__ b1p,
    float* __restrict__ c1t, float* __restrict__ c2t,
    const float* __restrict__ wp, const float* __restrict__ bp,
    float* __restrict__ y, int t2, int only_l1) {
  __shared__ alignas(16) bf16 hst_all[4 * 2304];   // 18 KB (epilogue only)
  int bid = (int)blockIdx.x;
  if (only_l1 || bid >= 256) {
    int v = only_l1 ? bid : bid - 256;
    int t1 = t2 + 1;
    if (t1 >= TT) return;
    int x = v & 7, r = v >> 3;
    int tm = (r & 15) << 7;
    int tn = ((x << 1) + (r >> 4)) << 8;
    body<0>(tm, tn, t1, Xf + (size_t)t1 * BB * 64, H1in,
            Wf0, b0p, c1t, H1out, nullptr, bp, y, hst_all);
  } else {
    int x = bid & 7, r = bid >> 3;
    int tm = (r & 15) << 7;
    int tn = ((x << 1) + (r >> 4)) << 8;
    body<1>(tm, tn, t2, H1in, H2in,
            Wf1, b1p, c2t, H2out, wp, nullptr, y, hst_all);
  }
}

// ---------------- launch ----------------

extern "C" void kernel_launch(void* const* d_in, const int* in_sizes, int n_in,
                              void* d_out, int out_size, void* d_ws, size_t ws_size,
                              hipStream_t stream) {
  const float* dec   = (const float*)d_in[0];
  const float* ty    = (const float*)d_in[1];
  const float* enc_h = (const float*)d_in[2];
  const float* enc_c = (const float*)d_in[3];
  const float* lec   = (const float*)d_in[4];
  const int*   gid   = (const int*)d_in[5];
  const int*   cp    = (const int*)d_in[6];
  const int*   cct   = (const int*)d_in[7];
  const int*   cpt   = (const int*)d_in[8];
  const int*   ccl   = (const int*)d_in[9];
  const float* gemb  = (const float*)d_in[10];
  const float* ep    = (const float*)d_in[11];
  const float* ect   = (const float*)d_in[12];
  const float* ept   = (const float*)d_in[13];
  const float* ecl   = (const float*)d_in[14];
  const float* Wih0  = (const float*)d_in[15];
  const float* Whh0  = (const float*)d_in[16];
  const float* b0    = (const float*)d_in[17];
  const float* Wih1  = (const float*)d_in[18];
  const float* Whh1  = (const float*)d_in[19];
  const float* b1    = (const float*)d_in[20];
  const float* wp    = (const float*)d_in[21];
  const float* bp    = (const float*)d_in[22];
  float* y = (float*)d_out;

  char* ws = (char*)d_ws;
  bf16* Wf1   = (bf16*)ws;  ws += (size_t)16 * NT1 * 8192 * 2;  // 16.8 MB
  bf16* Wf0   = (bf16*)ws;  ws += (size_t)16 * NT0 * 8192 * 2;  //  8.9 MB
  bf16* Xf    = (bf16*)ws;  ws += (size_t)BB * TT * 64 * 2;     // 25.2 MB
  bf16* H1a   = (bf16*)ws;  ws += (size_t)BB * 1024 * 2;        //  4.2 MB each
  bf16* H1b   = (bf16*)ws;  ws += (size_t)BB * 1024 * 2;
  bf16* H2a   = (bf16*)ws;  ws += (size_t)BB * 1024 * 2;
  bf16* H2b   = (bf16*)ws;  ws += (size_t)BB * 1024 * 2;
  float* c1t  = (float*)ws; ws += (size_t)BB * 1024 * 4;        //  8.4 MB
  float* c2t  = (float*)ws; ws += (size_t)BB * 1024 * 4;        //  8.4 MB
  float* b0p  = (float*)ws; ws += (size_t)NG * 4;
  float* b1p  = (float*)ws; ws += (size_t)NG * 4;

  build_wf1<<<(16 * NT1 * 8192) / 256, 256, 0, stream>>>(Wih1, Whh1, Wf1);
  build_wf0<<<(16 * NT0 * 8192 + 255) / 256, 256, 0, stream>>>(Wih0, Whh0, Wf0);
  perm_bias<<<NG / 256, 256, 0, stream>>>(b0, b1, b0p, b1p);
  build_xf<<<(BB * TT + 255) / 256, 256, 0, stream>>>(dec, ty, lec, gid, cp, cct, cpt, ccl,
                                                      gemb, ep, ect, ept, ecl, Xf);
  init_state<<<(BB * 1024) / 256, 256, 0, stream>>>(enc_h, enc_c, H1b, H2b, c1t, c2t);

  // prologue: L1(0) alone (grid 256). h1(t) in H1[t&1]; h2(t) in H2[t&1].
  step_kernel<<<256, 256, 0, stream>>>(H1b, nullptr, H1a, nullptr, Xf, Wf0, Wf1,
                                       b0p, b1p, c1t, c2t, wp, bp, y, -1, 1);
  for (int t = 0; t < TT; ++t) {
    bf16* h1i = (t & 1) ? H1b : H1a;
    bf16* h1o = (t & 1) ? H1a : H1b;
    bf16* h2i = (t & 1) ? H2a : H2b;
    bf16* h2o = (t & 1) ? H2b : H2a;
    step_kernel<<<512, 256, 0, stream>>>(h1i, h2i, h1o, h2o, Xf, Wf0, Wf1,
                                         b0p, b1p, c1t, c2t, wp, bp, y, t, 0);
  }
}

// Round 18
// 5841.933 us; speedup vs baseline: 2.0511x; 1.0280x over previous
//
#include <hip/hip_runtime.h>
#include <hip/hip_bf16.h>
#include <stdint.h>

// Decoder: 2-layer LSTM, B=2048, T=96, H=1024, teacher forcing=1.0.
// Round 18: R14/R16 champion with the K-loop scheduling fences REMOVED
// (no sched_barrier, no setprio) — the compiler interleaves loads among
// MFMAs with counted vmcnt (m97 behavior), spreading latency instead of
// draining it at a pinned cluster boundary. A-first load order for gradual
// first-use waits. hst pad 36 kept (0 conflicts). Everything else identical.

#define BB  2048
#define TT  96
#define NG  4096
#define NT0 34        // L1 K-iters (K=1088 = 2x32 x-part + 32x32 h-part)
#define NT1 64        // L2 K-iters (K=2048)

typedef __bf16 bf16;
typedef __bf16 bf16x8 __attribute__((ext_vector_type(8)));
typedef float  f32x4  __attribute__((ext_vector_type(4)));

__device__ __forceinline__ float sigm(float x) { return 1.0f / (1.0f + __expf(-x)); }
__device__ __forceinline__ float ftanh(float x) { return 2.0f / (1.0f + __expf(-2.0f * x)) - 1.0f; }

// ---------------- prep kernels ----------------
// Gate-interleaved n' = h*4 + gate (orig row n = (n'&3)*1024 + (n'>>2)).
// Wfrag: [panel(256g)][kt][wg(2)][gf(8)][lane(64)][j(8)].
// Afrag (H, X): tile (b>>4, k>>3) of 16x8 stored contiguous 128 elems:
//   off = ((b>>4)*K8 + (k>>3))*128 + (b&15)*8 + (k&7);  K8 = 128 (H), 8 (X).

__global__ __launch_bounds__(256) void build_wf1(const float* __restrict__ Wih1,
                                                 const float* __restrict__ Whh1,
                                                 bf16* __restrict__ Wf) {
  int idx = blockIdx.x * 256 + threadIdx.x;      // 16*64*8192
  if (idx >= 16 * NT1 * 8192) return;
  int j = idx & 7, lane = (idx >> 3) & 63, gf = (idx >> 9) & 7;
  int wg = (idx >> 12) & 1, kt = (idx >> 13) & 63, panel = idx >> 19;
  int np = panel * 256 + wg * 128 + gf * 16 + (lane & 15);
  int k  = kt * 32 + ((lane >> 4) << 3) + j;
  int n  = (np & 3) * 1024 + (np >> 2);
  float v = (k < 1024) ? Wih1[n * 1024 + k] : Whh1[n * 1024 + (k - 1024)];
  Wf[idx] = (bf16)v;
}

__global__ __launch_bounds__(256) void build_wf0(const float* __restrict__ Wih0,
                                                 const float* __restrict__ Whh0,
                                                 bf16* __restrict__ Wf) {
  int idx = blockIdx.x * 256 + threadIdx.x;      // 16*34*8192
  if (idx >= 16 * NT0 * 8192) return;
  int j = idx & 7, lane = (idx >> 3) & 63, gf = (idx >> 9) & 7;
  int wg = (idx >> 12) & 1;
  int rem = idx >> 13;
  int kt = rem % NT0, panel = rem / NT0;
  int np = panel * 256 + wg * 128 + gf * 16 + (lane & 15);
  int k  = kt * 32 + ((lane >> 4) << 3) + j;
  int n  = (np & 3) * 1024 + (np >> 2);
  float v;
  if (k < 60)      v = Wih0[n * 60 + k];
  else if (k < 64) v = 0.0f;
  else             v = Whh0[n * 1024 + (k - 64)];
  Wf[idx] = (bf16)v;
}

__global__ __launch_bounds__(256) void perm_bias(const float* __restrict__ b0,
                                                 const float* __restrict__ b1,
                                                 float* __restrict__ b0p,
                                                 float* __restrict__ b1p) {
  int idx = blockIdx.x * 256 + threadIdx.x;
  if (idx >= NG) return;
  int n = (idx & 3) * 1024 + (idx >> 2);
  b0p[idx] = b0[n];
  b1p[idx] = b1[n];
}

// Xf: per-t slab of 2048*64 elems, 16x8-tiled (K8 = 8)
__global__ __launch_bounds__(256) void build_xf(
    const float* __restrict__ dec, const float* __restrict__ ty, const float* __restrict__ lec,
    const int* __restrict__ gid, const int* __restrict__ cp, const int* __restrict__ cct,
    const int* __restrict__ cpt, const int* __restrict__ ccl,
    const float* __restrict__ gemb, const float* __restrict__ ep, const float* __restrict__ ect,
    const float* __restrict__ ept, const float* __restrict__ ecl,
    bf16* __restrict__ Xf) {
  int idx = blockIdx.x * 256 + threadIdx.x;  // over B*T
  if (idx >= BB * TT) return;
  int b = idx / TT, t = idx % TT;
  float xv[64];
  xv[0] = (t == 0) ? lec[b] : ty[b * TT + t - 1];
  const float* d = dec + (size_t)idx * 32;
  #pragma unroll
  for (int k = 0; k < 32; ++k) xv[1 + k] = d[k];
  const float* e;
  e = ep  + cp[b]  * 4;  for (int j = 0; j < 4;  ++j) xv[33 + j] = e[j];
  e = ect + cct[b] * 2;  for (int j = 0; j < 2;  ++j) xv[37 + j] = e[j];
  e = ept + cpt[b] * 3;  for (int j = 0; j < 3;  ++j) xv[39 + j] = e[j];
  e = ecl + ccl[b] * 2;  for (int j = 0; j < 2;  ++j) xv[42 + j] = e[j];
  e = gemb + gid[b] * 16; for (int j = 0; j < 16; ++j) xv[44 + j] = e[j];
  for (int j = 60; j < 64; ++j) xv[j] = 0.0f;
  bf16* slab = Xf + (size_t)t * BB * 64;
  int bt = b >> 4, bl = b & 15;
  #pragma unroll
  for (int k = 0; k < 64; ++k)
    slab[((size_t)(bt * 8 + (k >> 3)) << 7) + bl * 8 + (k & 7)] = (bf16)xv[k];
}

// enc state -> Hf fragment layout (K8=128) + transposed c ([h][b])
__global__ __launch_bounds__(256) void init_state(const float* __restrict__ enc_h,
                                                  const float* __restrict__ enc_c,
                                                  bf16* __restrict__ H1b,
                                                  bf16* __restrict__ H2b,
                                                  float* __restrict__ c1t,
                                                  float* __restrict__ c2t) {
  int idx = blockIdx.x * 256 + threadIdx.x;  // over B*H
  if (idx >= BB * 1024) return;
  int b = idx >> 10, h = idx & 1023;
  size_t off = ((size_t)((b >> 4) * 128 + (h >> 3)) << 7) + ((b & 15) << 3) + (h & 7);
  H1b[off] = (bf16)enc_h[idx];
  H2b[off] = (bf16)enc_h[(size_t)BB * 1024 + idx];
  c1t[(size_t)h * BB + b] = enc_c[idx];
  c2t[(size_t)h * BB + b] = enc_c[(size_t)BB * 1024 + idx];
}

// ---------------- streaming GEMM + fused cell: 128b x 256g, 4 waves --------
// gates(b,n') = A(b,:).W(n',:). mfma(wf, af): lane's f32x4 = {i,f,g,o} of one
// (b,h) cell: h = (tn>>2) + wg*32 + gf*4 + u, b = tm + wb*64 + bf*16 + l15.
// Both operands stream global->reg; K-loop is fence-free: the compiler
// interleaves the 12 loads among the 32 MFMAs with counted vmcnt waits.

template <int MODE>
__device__ __forceinline__ void body(
    int tm, int tn, int t,
    const bf16* __restrict__ P0, const bf16* __restrict__ P1,
    const bf16* __restrict__ Wf, const float* __restrict__ bperm,
    float* __restrict__ ct, bf16* __restrict__ Hout,
    const float* __restrict__ wp, const float* __restrict__ bp,
    float* __restrict__ y, bf16* hst_all)
{
  constexpr int NT = MODE ? NT1 : NT0;

  const int tid = threadIdx.x;
  const int lane = tid & 63, w = tid >> 6;
  const int lrow = lane & 15, u = lane >> 4;
  const int wb = w & 1, wg = w >> 1;

  f32x4 acc[8][4];
  #pragma unroll
  for (int gf = 0; gf < 8; ++gf)
    #pragma unroll
    for (int bf = 0; bf < 4; ++bf) acc[gf][bf] = (f32x4){0.f, 0.f, 0.f, 0.f};

  // A fragments: per-wave 1KB coalesced chunk per bf
  const int aoff = (u << 7) + (lrow << 3);       // lane offset within 512-elem chunk
  const int BtB = (tm >> 4) + wb * 4;            // base b-tile

  auto loadA = [&](bf16x8 (&af)[4], int kt) {
    #pragma unroll
    for (int bf = 0; bf < 4; ++bf) {
      const bf16* p;
      if constexpr (MODE == 0) {
        p = (kt < 2) ? P0 + ((size_t)((BtB + bf) * 8 + kt * 4) << 7) + aoff
                     : P1 + ((size_t)((BtB + bf) * 128 + (kt - 2) * 4) << 7) + aoff;
      } else {
        p = (kt < 32) ? P0 + ((size_t)((BtB + bf) * 128 + kt * 4) << 7) + aoff
                      : P1 + ((size_t)((BtB + bf) * 128 + (kt - 32) * 4) << 7) + aoff;
      }
      af[bf] = *reinterpret_cast<const bf16x8*>(p);
    }
  };

  // W fragments: [panel][kt][wg][gf][lane][8]
  const bf16* wfbase = Wf + (size_t)(tn >> 8) * NT * 8192 + wg * 4096 + lane * 8;
  auto loadW = [&](bf16x8 (&wf)[8], int kt) {
    const bf16* p = wfbase + (size_t)kt * 8192;
    #pragma unroll
    for (int gf = 0; gf < 8; ++gf)
      wf[gf] = *reinterpret_cast<const bf16x8*>(p + gf * 512);
  };

  bf16x8 afA[4], afB[4], wfA[8], wfB[8];

  // A issued first, W second: first MFMA (gf0,bf0) waits only to vmcnt(7),
  // then each successive gf releases one more W load — gradual, no full drain.
  loadA(afA, 0); loadW(wfA, 0);
  for (int kt = 0; kt < NT; kt += 2) {
    if (kt + 1 < NT) { loadA(afB, kt + 1); loadW(wfB, kt + 1); }
    #pragma unroll
    for (int gf = 0; gf < 8; ++gf)
      #pragma unroll
      for (int bf = 0; bf < 4; ++bf)
        acc[gf][bf] = __builtin_amdgcn_mfma_f32_16x16x32_bf16(wfA[gf], afA[bf], acc[gf][bf], 0, 0, 0);
    if (kt + 2 < NT) { loadA(afA, kt + 2); loadW(wfA, kt + 2); }
    #pragma unroll
    for (int gf = 0; gf < 8; ++gf)
      #pragma unroll
      for (int bf = 0; bf < 4; ++bf)
        acc[gf][bf] = __builtin_amdgcn_mfma_f32_16x16x32_bf16(wfB[gf], afB[bf], acc[gf][bf], 0, 0, 0);
  }

  // ---- fused cell epilogue (per-wave private LDS transpose; no barriers) ----
  // hst stride 36 (72B): stride-32's 16-bank-step conflict eliminated (0 measured).
  bf16* hst = hst_all + w * 2304;       // [64 b][36-padded 32 h] bf16
  const int hq = (tn >> 2) + wg * 32;   // wave h base (32 h values)
  const int bgb = tm + wb * 64;         // wave batch base (64 rows)
  float yp[4] = {0.f, 0.f, 0.f, 0.f};

  #pragma unroll
  for (int gf = 0; gf < 8; ++gf) {
    int hg = hq + gf * 4 + u;
    f32x4 bv = *reinterpret_cast<const f32x4*>(&bperm[hg * 4]);
    float wph = 0.f;
    if constexpr (MODE == 1) wph = wp[hg];
    #pragma unroll
    for (int bf = 0; bf < 4; ++bf) {
      int bg = bgb + bf * 16 + lrow;
      float gi = acc[gf][bf][0] + bv[0];
      float gf_ = acc[gf][bf][1] + bv[1];
      float gg = acc[gf][bf][2] + bv[2];
      float go = acc[gf][bf][3] + bv[3];
      float* cp_ = ct + (size_t)hg * BB + bg;
      float c = *cp_;
      float cn = sigm(gf_) * c + sigm(gi) * ftanh(gg);
      float hn = sigm(go) * ftanh(cn);
      *cp_ = cn;
      hst[(bf * 16 + lrow) * 36 + gf * 4 + u] = (bf16)hn;
      if constexpr (MODE == 1) yp[bf] += hn * wph;
    }
  }

  asm volatile("s_waitcnt lgkmcnt(0)" ::: "memory");
  __builtin_amdgcn_sched_barrier(0);

  // H write in fragment layout: chunk row=b_local (0..63), seg = 8-h group.
  #pragma unroll
  for (int q = 0; q < 4; ++q) {
    int chunk = q * 64 + lane;          // 0..255
    int row = chunk >> 2, seg = chunk & 3;
    bf16x8 v = *reinterpret_cast<const bf16x8*>(&hst[row * 36 + seg * 8]);
    size_t off = ((size_t)(((bgb >> 4) + (row >> 4)) * 128 + (hq >> 3) + seg) << 7)
               + ((row & 15) << 3);
    *reinterpret_cast<bf16x8*>(&Hout[off]) = v;
  }

  if constexpr (MODE == 1) {
    #pragma unroll
    for (int bf = 0; bf < 4; ++bf) {
      float s = yp[bf];
      s += __shfl_xor(s, 16);
      s += __shfl_xor(s, 32);
      if (lane < 16)
        atomicAdd(&y[(size_t)(bgb + bf * 16 + lane) * TT + t], s);
    }
  } else {
    if (tn == 0 && tid < 128) y[(size_t)(tm + tid) * TT + t] = bp[0];
  }
}

// Grid 512: bids [0,256) = L2(t); [256,512) = L1(t+1) (CU pairs one of each).
// Decode (XCD-stable panels): x=v&7, r=v>>3: tm=(r&15)*128, tn=(x*2+(r>>4))*256.
__global__ __launch_bounds__(256, 2) void step_kernel(
    const bf16* __restrict__ H1in, const bf16* __restrict__ H2in,
    bf16* __restrict__ H1out, bf16* __restrict__ H2out,
    const bf16* __restrict__ Xf,
    const bf16* __restrict__ Wf0, const bf16* __restrict__ Wf1,
    const float* __restrict__ b0p, const float* __restrict__ b1p,
    float* __restrict__ c1t, float* __restrict__ c2t,
    const float* __restrict__ wp, const float* __restrict__ bp,
    float* __restrict__ y, int t2, int only_l1) {
  __shared__ alignas(16) bf16 hst_all[4 * 2304];   // 18 KB (epilogue only)
  int bid = (int)blockIdx.x;
  if (only_l1 || bid >= 256) {
    int v = only_l1 ? bid : bid - 256;
    int t1 = t2 + 1;
    if (t1 >= TT) return;
    int x = v & 7, r = v >> 3;
    int tm = (r & 15) << 7;
    int tn = ((x << 1) + (r >> 4)) << 8;
    body<0>(tm, tn, t1, Xf + (size_t)t1 * BB * 64, H1in,
            Wf0, b0p, c1t, H1out, nullptr, bp, y, hst_all);
  } else {
    int x = bid & 7, r = bid >> 3;
    int tm = (r & 15) << 7;
    int tn = ((x << 1) + (r >> 4)) << 8;
    body<1>(tm, tn, t2, H1in, H2in,
            Wf1, b1p, c2t, H2out, wp, nullptr, y, hst_all);
  }
}

// ---------------- launch ----------------

extern "C" void kernel_launch(void* const* d_in, const int* in_sizes, int n_in,
                              void* d_out, int out_size, void* d_ws, size_t ws_size,
                              hipStream_t stream) {
  const float* dec   = (const float*)d_in[0];
  const float* ty    = (const float*)d_in[1];
  const float* enc_h = (const float*)d_in[2];
  const float* enc_c = (const float*)d_in[3];
  const float* lec   = (const float*)d_in[4];
  const int*   gid   = (const int*)d_in[5];
  const int*   cp    = (const int*)d_in[6];
  const int*   cct   = (const int*)d_in[7];
  const int*   cpt   = (const int*)d_in[8];
  const int*   ccl   = (const int*)d_in[9];
  const float* gemb  = (const float*)d_in[10];
  const float* ep    = (const float*)d_in[11];
  const float* ect   = (const float*)d_in[12];
  const float* ept   = (const float*)d_in[13];
  const float* ecl   = (const float*)d_in[14];
  const float* Wih0  = (const float*)d_in[15];
  const float* Whh0  = (const float*)d_in[16];
  const float* b0    = (const float*)d_in[17];
  const float* Wih1  = (const float*)d_in[18];
  const float* Whh1  = (const float*)d_in[19];
  const float* b1    = (const float*)d_in[20];
  const float* wp    = (const float*)d_in[21];
  const float* bp    = (const float*)d_in[22];
  float* y = (float*)d_out;

  char* ws = (char*)d_ws;
  bf16* Wf1   = (bf16*)ws;  ws += (size_t)16 * NT1 * 8192 * 2;  // 16.8 MB
  bf16* Wf0   = (bf16*)ws;  ws += (size_t)16 * NT0 * 8192 * 2;  //  8.9 MB
  bf16* Xf    = (bf16*)ws;  ws += (size_t)BB * TT * 64 * 2;     // 25.2 MB
  bf16* H1a   = (bf16*)ws;  ws += (size_t)BB * 1024 * 2;        //  4.2 MB each
  bf16* H1b   = (bf16*)ws;  ws += (size_t)BB * 1024 * 2;
  bf16* H2a   = (bf16*)ws;  ws += (size_t)BB * 1024 * 2;
  bf16* H2b   = (bf16*)ws;  ws += (size_t)BB * 1024 * 2;
  float* c1t  = (float*)ws; ws += (size_t)BB * 1024 * 4;        //  8.4 MB
  float* c2t  = (float*)ws; ws += (size_t)BB * 1024 * 4;        //  8.4 MB
  float* b0p  = (float*)ws; ws += (size_t)NG * 4;
  float* b1p  = (float*)ws; ws += (size_t)NG * 4;

  build_wf1<<<(16 * NT1 * 8192) / 256, 256, 0, stream>>>(Wih1, Whh1, Wf1);
  build_wf0<<<(16 * NT0 * 8192 + 255) / 256, 256, 0, stream>>>(Wih0, Whh0, Wf0);
  perm_bias<<<NG / 256, 256, 0, stream>>>(b0, b1, b0p, b1p);
  build_xf<<<(BB * TT + 255) / 256, 256, 0, stream>>>(dec, ty, lec, gid, cp, cct, cpt, ccl,
                                                      gemb, ep, ect, ept, ecl, Xf);
  init_state<<<(BB * 1024) / 256, 256, 0, stream>>>(enc_h, enc_c, H1b, H2b, c1t, c2t);

  // prologue: L1(0) alone (grid 256). h1(t) in H1[t&1]; h2(t) in H2[t&1].
  step_kernel<<<256, 256, 0, stream>>>(H1b, nullptr, H1a, nullptr, Xf, Wf0, Wf1,
                                       b0p, b1p, c1t, c2t, wp, bp, y, -1, 1);
  for (int t = 0; t < TT; ++t) {
    bf16* h1i = (t & 1) ? H1b : H1a;
    bf16* h1o = (t & 1) ? H1a : H1b;
    bf16* h2i = (t & 1) ? H2a : H2b;
    bf16* h2o = (t & 1) ? H2b : H2a;
    step_kernel<<<512, 256, 0, stream>>>(h1i, h2i, h1o, h2o, Xf, Wf0, Wf1,
                                         b0p, b1p, c1t, c2t, wp, bp, y, t, 0);
  }
}